// Round 3
// baseline (263.483 us; speedup 1.0000x reference)
//
#include <hip/hip_runtime.h>

#define BB 2
#define SS 4096
#define EE 768
#define HH 12
#define DD 64
#define WW 256

typedef __attribute__((ext_vector_type(8))) short short8;
typedef __attribute__((ext_vector_type(4))) short short4v;
typedef __attribute__((ext_vector_type(4))) float floatx4;

#define MFMA16(a, b, c) __builtin_amdgcn_mfma_f32_16x16x32_bf16(a, b, c, 0, 0, 0)

__device__ __forceinline__ float bf2f(short x) {
    union { unsigned u; float f; } v;
    v.u = ((unsigned)(unsigned short)x) << 16;
    return v.f;
}

__device__ __forceinline__ short f2bf(float x) {
    union { float f; unsigned u; } v;
    v.f = x;
    unsigned r = v.u + 0x7fffu + ((v.u >> 16) & 1u);  // RNE
    return (short)(r >> 16);
}

__device__ __forceinline__ int imin(int a, int b) { return a < b ? a : b; }
__device__ __forceinline__ int imax(int a, int b) { return a > b ? a : b; }

// out[c][r] = bf16(in[r][c])  — fp32 -> bf16 transpose for the weight matrices
__global__ void transpose_w(const float* __restrict__ in, short* __restrict__ out,
                            int R, int C) {
    __shared__ short t[32][33];
    int tx = threadIdx.x, ty = threadIdx.y;  // 32 x 8
    int x = blockIdx.x * 32 + tx;
    int y0 = blockIdx.y * 32;
    for (int j = 0; j < 32; j += 8) t[ty + j][tx] = f2bf(in[(size_t)(y0 + ty + j) * C + x]);
    __syncthreads();
    int x2 = y0 + tx;
    int y2 = blockIdx.x * 32;
    for (int j = 0; j < 32; j += 8) out[(size_t)(y2 + ty + j) * R + x2] = t[tx][ty + j];
}

// C = X * W^T(+bias), X fp32:[8192][768], Wt bf16:[3][768(n)][768(k)]
// z=0: Q*(1/8) -> [B,H,S,D] bf16;  z=1: K -> [B,H,S,D] bf16;  z=2: V -> [B,H,D,S] bf16
__global__ __launch_bounds__(256) void qkv_gemm(
    const float* __restrict__ X, const short* __restrict__ Wt,
    const float* __restrict__ Bq, const float* __restrict__ Bk, const float* __restrict__ Bv,
    short* __restrict__ Qo, short* __restrict__ Ko, short* __restrict__ Vto) {
    const int Kd = EE;
    int z = blockIdx.z;
    const short* Wz = Wt + (size_t)z * EE * EE;
    const float* bias = (z == 0) ? Bq : (z == 1) ? Bk : Bv;

    __shared__ __align__(16) short As[128 * 40];
    __shared__ __align__(16) short Bs[128 * 40];
    int tid = threadIdx.x;
    int m0 = blockIdx.x * 128, n0 = blockIdx.y * 128;
    int wave = tid >> 6, lane = tid & 63, lquad = lane >> 4, lrow = lane & 15;
    int wm = (wave & 1) * 64, wn = (wave >> 1) * 64;

    floatx4 acc[4][4] = {};
    int sr = tid >> 2;         // 0..63
    int scol = (tid & 3) * 8;  // 0,8,16,24

    for (int k0 = 0; k0 < Kd; k0 += 32) {
        for (int i = 0; i < 2; i++) {
            int row = sr + i * 64;
            const floatx4* src = (const floatx4*)&X[(size_t)(m0 + row) * Kd + k0 + scol];
            floatx4 f0 = src[0], f1 = src[1];
            short8 s8;
#pragma unroll
            for (int j = 0; j < 4; j++) { s8[j] = f2bf(f0[j]); s8[j + 4] = f2bf(f1[j]); }
            *(short8*)&As[row * 40 + scol] = s8;
            *(short8*)&Bs[row * 40 + scol] =
                *(const short8*)&Wz[(size_t)(n0 + row) * Kd + k0 + scol];
        }
        __syncthreads();
        short8 af[4], bfv[4];
        for (int mt = 0; mt < 4; mt++)
            af[mt] = *(short8*)&As[(wm + mt * 16 + lrow) * 40 + lquad * 8];
        for (int nt = 0; nt < 4; nt++)
            bfv[nt] = *(short8*)&Bs[(wn + nt * 16 + lrow) * 40 + lquad * 8];
        for (int mt = 0; mt < 4; mt++)
            for (int nt = 0; nt < 4; nt++)
                acc[mt][nt] = MFMA16(af[mt], bfv[nt], acc[mt][nt]);
        __syncthreads();
    }

    if (z == 2) {
        // V, stored transposed: Vt[b,h,d,s]
        for (int nt = 0; nt < 4; nt++) {
            int gn = n0 + wn + nt * 16 + lrow;
            float bv = bias[gn];
            int h = gn >> 6, d = gn & 63;
            for (int mt = 0; mt < 4; mt++) {
                int gm0 = m0 + wm + mt * 16 + lquad * 4;  // multiple of 4
                int b = gm0 >> 12, s = gm0 & (SS - 1);
                short4v pk;
                for (int r = 0; r < 4; r++) pk[r] = f2bf(acc[mt][nt][r] + bv);
                *(short4v*)&Vto[(((size_t)(b * HH + h)) * DD + d) * SS + s] = pk;
            }
        }
    } else {
        short* out = (z == 0) ? Qo : Ko;
        float scale = (z == 0) ? 0.125f : 1.0f;
        for (int nt = 0; nt < 4; nt++) {
            int gn = n0 + wn + nt * 16 + lrow;
            float bv = bias[gn];
            int h = gn >> 6, d = gn & 63;
            for (int mt = 0; mt < 4; mt++) {
                int gmb = m0 + wm + mt * 16 + lquad * 4;
                for (int r = 0; r < 4; r++) {
                    int gm = gmb + r;
                    int b = gm >> 12, s = gm & (SS - 1);
                    float v = (acc[mt][nt][r] + bv) * scale;
                    out[(((size_t)(b * HH + h)) * SS + s) * DD + d] = f2bf(v);
                }
            }
        }
    }
}

// Sliding-window attention, unshifted softmax (scores bounded: Q pre-scaled).
// Q,K bf16: [B,H,S,D]; Vt bf16: [B,H,D,S]; out fp32: [B,S,E]
__global__ __launch_bounds__(256) void band_attn(
    const short* __restrict__ Q, const short* __restrict__ K,
    const short* __restrict__ Vt, float* __restrict__ out) {
    int b = blockIdx.z, h = blockIdx.y, chunk = blockIdx.x;
    int tid = threadIdx.x;
    int wave = tid >> 6, lane = tid & 63, lquad = lane >> 4, lrow = lane & 15;
    int r0 = chunk * 64 + wave * 16;

    const short* Qh = Q + ((size_t)(b * HH + h)) * SS * DD;
    const short* Kh = K + ((size_t)(b * HH + h)) * SS * DD;
    const short* Vh = Vt + ((size_t)(b * HH + h)) * DD * SS;

    __shared__ __align__(16) short P[4][16 * 40];
    short* Pw = &P[wave][0];

    // Q fragments: A[m=lrow][k=lquad*8+j], two K=32 halves of D=64
    short8 qf0 = *(const short8*)&Qh[(size_t)(r0 + lrow) * DD + lquad * 8];
    short8 qf1 = *(const short8*)&Qh[(size_t)(r0 + lrow) * DD + 32 + lquad * 8];

    floatx4 o[4] = {};
    float ls[4] = {0.0f, 0.0f, 0.0f, 0.0f};

    int base = r0 - WW;
    for (int t = 0; t < 17; t++) {  // uniform trip count: covers [r0-256, r0+287]
        int ks = base + t * 32;
        short pb[2][4];
        for (int kt = 0; kt < 2; kt++) {
            int key = ks + kt * 16 + lrow;
            int kc = imin(imax(key, 0), SS - 1);
            short8 kf0 = *(const short8*)&Kh[(size_t)kc * DD + lquad * 8];
            short8 kf1 = *(const short8*)&Kh[(size_t)kc * DD + 32 + lquad * 8];
            floatx4 s4 = {};
            s4 = MFMA16(qf0, kf0, s4);
            s4 = MFMA16(qf1, kf1, s4);
            for (int r = 0; r < 4; r++) {
                int row = r0 + lquad * 4 + r;
                bool valid = (key >= row - WW) && (key <= row + WW) && (key >= 0) && (key < SS);
                float p = valid ? __expf(s4[r]) : 0.0f;
                short pbv = f2bf(p);
                pb[kt][r] = pbv;
                ls[r] += bf2f(pbv);  // normalize with the same rounded p used in PV
            }
        }
        // C-layout -> A-layout round-trip through per-wave LDS
        for (int kt = 0; kt < 2; kt++)
            for (int r = 0; r < 4; r++)
                Pw[(lquad * 4 + r) * 40 + kt * 16 + lrow] = pb[kt][r];
        __syncthreads();
        short8 ap = *(short8*)&Pw[lrow * 40 + lquad * 8];
        int kb = ks + lquad * 8;                 // multiple of 8
        int kcb = imin(imax(kb, 0), SS - 8);     // only shifts fully-masked groups (P=0)
        for (int nt = 0; nt < 4; nt++) {
            short8 vf = *(const short8*)&Vh[(size_t)(nt * 16 + lrow) * SS + kcb];
            o[nt] = MFMA16(ap, vf, o[nt]);
        }
        __syncthreads();
    }

    for (int r = 0; r < 4; r++)
        for (int d2 = 1; d2 < 16; d2 <<= 1)
            ls[r] += __shfl_xor(ls[r], d2, 64);

    for (int nt = 0; nt < 4; nt++) {
        for (int r = 0; r < 4; r++) {
            int s = r0 + lquad * 4 + r;
            out[((size_t)b * SS + s) * EE + h * DD + nt * 16 + lrow] = o[nt][r] / ls[r];
        }
    }
}

extern "C" void kernel_launch(void* const* d_in, const int* in_sizes, int n_in,
                              void* d_out, int out_size, void* d_ws, size_t ws_size,
                              hipStream_t stream) {
    const float* hidden = (const float*)d_in[0];
    const float* Wq = (const float*)d_in[1];
    const float* bq = (const float*)d_in[2];
    const float* Wk = (const float*)d_in[3];
    const float* bk = (const float*)d_in[4];
    const float* Wv = (const float*)d_in[5];
    const float* bv = (const float*)d_in[6];
    float* out = (float*)d_out;

    short* ws = (short*)d_ws;
    const size_t WSZ = (size_t)EE * EE;            // 589824
    const size_t QSZ = (size_t)BB * HH * SS * DD;  // 6291456
    short* Wt = ws;              // 3 * WSZ  (bf16)
    short* Qb = Wt + 3 * WSZ;    // Q  [B,H,S,D] bf16
    short* Kb = Qb + QSZ;        // K  [B,H,S,D] bf16
    short* Vtb = Kb + QSZ;       // Vt [B,H,D,S] bf16
    // total: 3*WSZ + 3*QSZ shorts = 41.3 MB

    dim3 tb(32, 8, 1);
    transpose_w<<<dim3(24, 24, 1), tb, 0, stream>>>(Wq, Wt + 0 * WSZ, EE, EE);
    transpose_w<<<dim3(24, 24, 1), tb, 0, stream>>>(Wk, Wt + 1 * WSZ, EE, EE);
    transpose_w<<<dim3(24, 24, 1), tb, 0, stream>>>(Wv, Wt + 2 * WSZ, EE, EE);

    qkv_gemm<<<dim3(64, 6, 3), 256, 0, stream>>>(hidden, Wt, bq, bk, bv, Qb, Kb, Vtb);

    band_attn<<<dim3(SS / 64, HH, BB), 256, 0, stream>>>(Qb, Kb, Vtb, out);
}

// Round 4
// 218.925 us; speedup vs baseline: 1.2035x; 1.2035x over previous
//
#include <hip/hip_runtime.h>

#define BB 2
#define SS 4096
#define EE 768
#define HH 12
#define DD 64
#define WW 256

typedef __attribute__((ext_vector_type(8))) short short8;
typedef __attribute__((ext_vector_type(4))) short short4v;
typedef __attribute__((ext_vector_type(4))) float floatx4;

#define MFMA16(a, b, c) __builtin_amdgcn_mfma_f32_16x16x32_bf16(a, b, c, 0, 0, 0)

__device__ __forceinline__ float bf2f(short x) {
    union { unsigned u; float f; } v;
    v.u = ((unsigned)(unsigned short)x) << 16;
    return v.f;
}

__device__ __forceinline__ short f2bf(float x) {
    union { float f; unsigned u; } v;
    v.f = x;
    unsigned r = v.u + 0x7fffu + ((v.u >> 16) & 1u);  // RNE
    return (short)(r >> 16);
}

__device__ __forceinline__ int imin(int a, int b) { return a < b ? a : b; }
__device__ __forceinline__ int imax(int a, int b) { return a > b ? a : b; }

// out[c][r] = bf16(in[r][c])  — fp32 -> bf16 transpose for the weight matrices
__global__ void transpose_w(const float* __restrict__ in, short* __restrict__ out,
                            int R, int C) {
    __shared__ short t[32][33];
    int tx = threadIdx.x, ty = threadIdx.y;  // 32 x 8
    int x = blockIdx.x * 32 + tx;
    int y0 = blockIdx.y * 32;
    for (int j = 0; j < 32; j += 8) t[ty + j][tx] = f2bf(in[(size_t)(y0 + ty + j) * C + x]);
    __syncthreads();
    int x2 = y0 + tx;
    int y2 = blockIdx.x * 32;
    for (int j = 0; j < 32; j += 8) out[(size_t)(y2 + ty + j) * R + x2] = t[tx][ty + j];
}

// C = X * W^T(+bias), X fp32:[8192][768], Wt bf16:[3][768(n)][768(k)]
// z=0: Q*(1/8) -> [B,H,S,D] bf16;  z=1: K -> [B,H,S,D] bf16;  z=2: V -> [B,H,D,S] bf16
__global__ __launch_bounds__(256) void qkv_gemm(
    const float* __restrict__ X, const short* __restrict__ Wt,
    const float* __restrict__ Bq, const float* __restrict__ Bk, const float* __restrict__ Bv,
    short* __restrict__ Qo, short* __restrict__ Ko, short* __restrict__ Vto) {
    const int Kd = EE;
    int z = blockIdx.z;
    const short* Wz = Wt + (size_t)z * EE * EE;
    const float* bias = (z == 0) ? Bq : (z == 1) ? Bk : Bv;

    __shared__ __align__(16) short As[128 * 40];
    __shared__ __align__(16) short Bs[128 * 40];
    int tid = threadIdx.x;
    int m0 = blockIdx.x * 128, n0 = blockIdx.y * 128;
    int wave = tid >> 6, lane = tid & 63, lquad = lane >> 4, lrow = lane & 15;
    int wm = (wave & 1) * 64, wn = (wave >> 1) * 64;

    floatx4 acc[4][4] = {};
    int sr = tid >> 2;         // 0..63
    int scol = (tid & 3) * 8;  // 0,8,16,24

    for (int k0 = 0; k0 < Kd; k0 += 32) {
        for (int i = 0; i < 2; i++) {
            int row = sr + i * 64;
            const floatx4* src = (const floatx4*)&X[(size_t)(m0 + row) * Kd + k0 + scol];
            floatx4 f0 = src[0], f1 = src[1];
            short8 s8;
#pragma unroll
            for (int j = 0; j < 4; j++) { s8[j] = f2bf(f0[j]); s8[j + 4] = f2bf(f1[j]); }
            *(short8*)&As[row * 40 + scol] = s8;
            *(short8*)&Bs[row * 40 + scol] =
                *(const short8*)&Wz[(size_t)(n0 + row) * Kd + k0 + scol];
        }
        __syncthreads();
        short8 af[4], bfv[4];
        for (int mt = 0; mt < 4; mt++)
            af[mt] = *(short8*)&As[(wm + mt * 16 + lrow) * 40 + lquad * 8];
        for (int nt = 0; nt < 4; nt++)
            bfv[nt] = *(short8*)&Bs[(wn + nt * 16 + lrow) * 40 + lquad * 8];
        for (int mt = 0; mt < 4; mt++)
            for (int nt = 0; nt < 4; nt++)
                acc[mt][nt] = MFMA16(af[mt], bfv[nt], acc[mt][nt]);
        __syncthreads();
    }

    if (z == 2) {
        // V, stored transposed: Vt[b,h,d,s]
        for (int nt = 0; nt < 4; nt++) {
            int gn = n0 + wn + nt * 16 + lrow;
            float bv = bias[gn];
            int h = gn >> 6, d = gn & 63;
            for (int mt = 0; mt < 4; mt++) {
                int gm0 = m0 + wm + mt * 16 + lquad * 4;  // multiple of 4
                int b = gm0 >> 12, s = gm0 & (SS - 1);
                short4v pk;
                for (int r = 0; r < 4; r++) pk[r] = f2bf(acc[mt][nt][r] + bv);
                *(short4v*)&Vto[(((size_t)(b * HH + h)) * DD + d) * SS + s] = pk;
            }
        }
    } else {
        short* out = (z == 0) ? Qo : Ko;
        float scale = (z == 0) ? 0.125f : 1.0f;
        for (int nt = 0; nt < 4; nt++) {
            int gn = n0 + wn + nt * 16 + lrow;
            float bv = bias[gn];
            int h = gn >> 6, d = gn & 63;
            for (int mt = 0; mt < 4; mt++) {
                int gmb = m0 + wm + mt * 16 + lquad * 4;
                for (int r = 0; r < 4; r++) {
                    int gm = gmb + r;
                    int b = gm >> 12, s = gm & (SS - 1);
                    float v = (acc[mt][nt][r] + bv) * scale;
                    out[(((size_t)(b * HH + h)) * SS + s) * DD + d] = f2bf(v);
                }
            }
        }
    }
}

// Sliding-window attention v2: 256 queries/block, K/V tiles staged in LDS and
// shared by all 4 waves. Scores computed transposed (S^T = K*Q^T) so the
// softmax/P-repack is cheap. Unshifted softmax (scores bounded; Q pre-scaled).
// Q,K bf16 [B,H,S,D]; Vt bf16 [B,H,D,S]; out fp32 [B,S,E].
__global__ __launch_bounds__(256) void band_attn(
    const short* __restrict__ Q, const short* __restrict__ K,
    const short* __restrict__ Vt, float* __restrict__ out) {
    int b = blockIdx.z, h = blockIdx.y, chunk = blockIdx.x;
    int tid = threadIdx.x;
    int wave = tid >> 6, lane = tid & 63, lquad = lane >> 4, lrow = lane & 15;
    int qbase = chunk * 256 + wave * 64;  // this wave's 64 queries

    const short* Qh = Q + ((size_t)(b * HH + h)) * SS * DD;
    const short* Kh = K + ((size_t)(b * HH + h)) * SS * DD;
    const short* Vh = Vt + ((size_t)(b * HH + h)) * DD * SS;

    __shared__ __align__(16) short Ks[64 * 72];      // [key][d]
    __shared__ __align__(16) short Vs[64 * 72];      // [d][key]
    __shared__ __align__(16) short Ps[4][16 * 72];   // per wave: [q][key]
    short* Pw = &Ps[wave][0];

    // Persistent Q B-fragments: B[n=query=lrow][k=d=lquad*8+j], two K=32 halves
    short8 qf[4][2];
#pragma unroll
    for (int m = 0; m < 4; m++)
#pragma unroll
        for (int hh = 0; hh < 2; hh++)
            qf[m][hh] = *(const short8*)&Qh[(size_t)(qbase + m * 16 + lrow) * DD + hh * 32 + lquad * 8];

    floatx4 o[4][4] = {};
    float ls[4] = {0.0f, 0.0f, 0.0f, 0.0f};

    int kwin = chunk * 256 - WW;  // block's key-window start (12 tiles of 64)
    int srow = tid >> 3;          // 0..31
    int scol = (tid & 7) * 8;     // 0..56

    for (int t = 0; t < 12; t++) {
        int ks0 = kwin + t * 64;
        // --- stage K tile [64 keys x 64 d] and Vt tile [64 d x 64 keys] ---
#pragma unroll
        for (int i = 0; i < 2; i++) {
            int r = srow + i * 32;
            int gk = imin(imax(ks0 + r, 0), SS - 1);
            *(short8*)&Ks[r * 72 + scol] = *(const short8*)&Kh[(size_t)gk * DD + scol];
            int gv = imin(imax(ks0 + scol, 0), SS - 8);
            *(short8*)&Vs[r * 72 + scol] = *(const short8*)&Vh[(size_t)r * SS + gv];
        }
        __syncthreads();

        if ((unsigned)(t - wave) < 9u) {  // this wave's 576-key window
            short8 kf[4][2], vf[4][2];
#pragma unroll
            for (int kt = 0; kt < 4; kt++)
#pragma unroll
                for (int hh = 0; hh < 2; hh++)
                    kf[kt][hh] = *(short8*)&Ks[(kt * 16 + lrow) * 72 + hh * 32 + lquad * 8];
#pragma unroll
            for (int nt = 0; nt < 4; nt++)
#pragma unroll
                for (int hh = 0; hh < 2; hh++)
                    vf[nt][hh] = *(short8*)&Vs[(nt * 16 + lrow) * 72 + hh * 32 + lquad * 8];

#pragma unroll
            for (int m = 0; m < 4; m++) {
                int q = qbase + m * 16 + lrow;  // this lane's query (S^T: col = lane&15)
                floatx4 s[4];
#pragma unroll
                for (int kt = 0; kt < 4; kt++) {
                    floatx4 zz = {};
                    s[kt] = MFMA16(kf[kt][0], qf[m][0], zz);
                    s[kt] = MFMA16(kf[kt][1], qf[m][1], s[kt]);
                }
                float lacc = 0.0f;
#pragma unroll
                for (int kt = 0; kt < 4; kt++) {
                    short4v pk;
#pragma unroll
                    for (int r = 0; r < 4; r++) {
                        int key = ks0 + kt * 16 + lquad * 4 + r;
                        bool valid = ((unsigned)(key - q + WW) <= 2u * WW) && ((unsigned)key < SS);
                        float p = valid ? __expf(s[kt][r]) : 0.0f;
                        pk[r] = f2bf(p);
                        lacc += bf2f(pk[r]);
                    }
                    // 4 consecutive keys for query lrow: one packed 8B store
                    *(short4v*)&Pw[lrow * 72 + kt * 16 + lquad * 4] = pk;
                }
                ls[m] += lacc;
                asm volatile("" ::: "memory");  // order P write->read (same-wave DS is in-order)
                short8 ap0 = *(short8*)&Pw[lrow * 72 + lquad * 8];
                short8 ap1 = *(short8*)&Pw[lrow * 72 + 32 + lquad * 8];
#pragma unroll
                for (int nt = 0; nt < 4; nt++) {
                    o[m][nt] = MFMA16(ap0, vf[nt][0], o[m][nt]);
                    o[m][nt] = MFMA16(ap1, vf[nt][1], o[m][nt]);
                }
            }
        }
        __syncthreads();
    }

    // ls[m] currently: per-lane partial over this lane's quad; reduce over quads
#pragma unroll
    for (int m = 0; m < 4; m++) {
        ls[m] += __shfl_xor(ls[m], 16, 64);
        ls[m] += __shfl_xor(ls[m], 32, 64);
        ls[m] = 1.0f / ls[m];  // lane L holds 1/ls for query (L&15)
    }

#pragma unroll
    for (int m = 0; m < 4; m++) {
#pragma unroll
        for (int r = 0; r < 4; r++) {
            float linv = __shfl(ls[m], lquad * 4 + r, 64);
            int s = qbase + m * 16 + lquad * 4 + r;
#pragma unroll
            for (int nt = 0; nt < 4; nt++)
                out[((size_t)b * SS + s) * EE + h * DD + nt * 16 + lrow] = o[m][nt][r] * linv;
        }
    }
}

extern "C" void kernel_launch(void* const* d_in, const int* in_sizes, int n_in,
                              void* d_out, int out_size, void* d_ws, size_t ws_size,
                              hipStream_t stream) {
    const float* hidden = (const float*)d_in[0];
    const float* Wq = (const float*)d_in[1];
    const float* bq = (const float*)d_in[2];
    const float* Wk = (const float*)d_in[3];
    const float* bk = (const float*)d_in[4];
    const float* Wv = (const float*)d_in[5];
    const float* bv = (const float*)d_in[6];
    float* out = (float*)d_out;

    short* ws = (short*)d_ws;
    const size_t WSZ = (size_t)EE * EE;            // 589824
    const size_t QSZ = (size_t)BB * HH * SS * DD;  // 6291456
    short* Wt = ws;              // 3 * WSZ  (bf16)
    short* Qb = Wt + 3 * WSZ;    // Q  [B,H,S,D] bf16
    short* Kb = Qb + QSZ;        // K  [B,H,S,D] bf16
    short* Vtb = Kb + QSZ;       // Vt [B,H,D,S] bf16
    // total: 3*WSZ + 3*QSZ shorts = 41.3 MB

    dim3 tb(32, 8, 1);
    transpose_w<<<dim3(24, 24, 1), tb, 0, stream>>>(Wq, Wt + 0 * WSZ, EE, EE);
    transpose_w<<<dim3(24, 24, 1), tb, 0, stream>>>(Wk, Wt + 1 * WSZ, EE, EE);
    transpose_w<<<dim3(24, 24, 1), tb, 0, stream>>>(Wv, Wt + 2 * WSZ, EE, EE);

    qkv_gemm<<<dim3(64, 6, 3), 256, 0, stream>>>(hidden, Wt, bq, bk, bv, Qb, Kb, Vtb);

    band_attn<<<dim3(SS / 256, HH, BB), 256, 0, stream>>>(Qb, Kb, Vtb, out);
}

// Round 5
// 196.028 us; speedup vs baseline: 1.3441x; 1.1168x over previous
//
#include <hip/hip_runtime.h>

#define BB 2
#define SS 4096
#define EE 768
#define HH 12
#define DD 64
#define WW 256

typedef __attribute__((ext_vector_type(8))) short short8;
typedef __attribute__((ext_vector_type(4))) short short4v;
typedef __attribute__((ext_vector_type(4))) float floatx4;

#define MFMA16(a, b, c) __builtin_amdgcn_mfma_f32_16x16x32_bf16(a, b, c, 0, 0, 0)

__device__ __forceinline__ float bf2f(short x) {
    union { unsigned u; float f; } v;
    v.u = ((unsigned)(unsigned short)x) << 16;
    return v.f;
}

__device__ __forceinline__ short f2bf(float x) {
    union { float f; unsigned u; } v;
    v.f = x;
    unsigned r = v.u + 0x7fffu + ((v.u >> 16) & 1u);  // RNE
    return (short)(r >> 16);
}

__device__ __forceinline__ int imin(int a, int b) { return a < b ? a : b; }
__device__ __forceinline__ int imax(int a, int b) { return a > b ? a : b; }

// async global->LDS, 16B per lane; LDS dest must be wave-uniform-base + lane*16
__device__ __forceinline__ void gload_lds16(const short* g, short* l) {
    __builtin_amdgcn_global_load_lds(
        (const __attribute__((address_space(1))) unsigned*)g,
        (__attribute__((address_space(3))) unsigned*)l, 16, 0, 0);
}

// fp32 -> bf16 bulk convert (X), 8 elems/thread
__global__ __launch_bounds__(256) void convert_x(const float* __restrict__ in,
                                                 short* __restrict__ out) {
    int i = blockIdx.x * 256 + threadIdx.x;
    const floatx4* src = (const floatx4*)(in + (size_t)i * 8);
    floatx4 f0 = src[0], f1 = src[1];
    short8 s8;
#pragma unroll
    for (int j = 0; j < 4; j++) { s8[j] = f2bf(f0[j]); s8[j + 4] = f2bf(f1[j]); }
    *(short8*)(out + (size_t)i * 8) = s8;
}

// out[z][c][r] = bf16(in_z[r][c]) for the three 768x768 weight matrices
__global__ void transpose_w(const float* __restrict__ W0, const float* __restrict__ W1,
                            const float* __restrict__ W2, short* __restrict__ out) {
    __shared__ short t[32][33];
    int z = blockIdx.z;
    const float* in = (z == 0) ? W0 : (z == 1) ? W1 : W2;
    short* op = out + (size_t)z * EE * EE;
    int tx = threadIdx.x, ty = threadIdx.y;  // 32 x 8
    int x = blockIdx.x * 32 + tx;
    int y0 = blockIdx.y * 32;
    for (int j = 0; j < 32; j += 8) t[ty + j][tx] = f2bf(in[(size_t)(y0 + ty + j) * EE + x]);
    __syncthreads();
    int x2 = y0 + tx;
    int y2 = blockIdx.x * 32;
    for (int j = 0; j < 32; j += 8) op[(size_t)(y2 + ty + j) * EE + x2] = t[tx][ty + j];
}

// C = Xb * W^T(+bias), Xb bf16:[8192][768], Wt bf16:[3][768(n)][768(k)]
// z=0: Q*(1/8) -> [B,H,S,D];  z=1: K -> [B,H,S,D];  z=2: V -> [B,H,D,S]
// m97 structure: unpadded LDS tiles + global_load_lds width-16 staging.
__global__ __launch_bounds__(256) void qkv_gemm(
    const short* __restrict__ Xb, const short* __restrict__ Wt,
    const float* __restrict__ Bq, const float* __restrict__ Bk, const float* __restrict__ Bv,
    short* __restrict__ Qo, short* __restrict__ Ko, short* __restrict__ Vto) {
    int z = blockIdx.z;
    const short* Wz = Wt + (size_t)z * EE * EE;
    const float* bias = (z == 0) ? Bq : (z == 1) ? Bk : Bv;

    __shared__ __align__(16) short As[128 * 32];
    __shared__ __align__(16) short Bs[128 * 32];
    int tid = threadIdx.x;
    int m0 = blockIdx.x * 128, n0 = blockIdx.y * 128;
    int wave = tid >> 6, lane = tid & 63, lquad = lane >> 4, lrow = lane & 15;
    int wm = (wave & 1) * 64, wn = (wave >> 1) * 64;

    floatx4 acc[4][4] = {};

    // staging chunks: c = j*256 + tid; row = c>>2, col = (c&3)*8 shorts
    int c0 = tid, c1 = 256 + tid;
    int r0s = c0 >> 2, c0s = (c0 & 3) * 8;
    int r1s = c1 >> 2, c1s = (c1 & 3) * 8;

    for (int k0 = 0; k0 < EE; k0 += 32) {
        gload_lds16(&Xb[(size_t)(m0 + r0s) * EE + k0 + c0s], &As[c0 * 8]);
        gload_lds16(&Wz[(size_t)(n0 + r0s) * EE + k0 + c0s], &Bs[c0 * 8]);
        gload_lds16(&Xb[(size_t)(m0 + r1s) * EE + k0 + c1s], &As[c1 * 8]);
        gload_lds16(&Wz[(size_t)(n0 + r1s) * EE + k0 + c1s], &Bs[c1 * 8]);
        __syncthreads();
        short8 af[4], bfv[4];
#pragma unroll
        for (int mt = 0; mt < 4; mt++)
            af[mt] = *(short8*)&As[(wm + mt * 16 + lrow) * 32 + lquad * 8];
#pragma unroll
        for (int nt = 0; nt < 4; nt++)
            bfv[nt] = *(short8*)&Bs[(wn + nt * 16 + lrow) * 32 + lquad * 8];
#pragma unroll
        for (int mt = 0; mt < 4; mt++)
#pragma unroll
            for (int nt = 0; nt < 4; nt++)
                acc[mt][nt] = MFMA16(af[mt], bfv[nt], acc[mt][nt]);
        __syncthreads();
    }

    if (z == 2) {
        // V, stored transposed: Vt[b,h,d,s]
        for (int nt = 0; nt < 4; nt++) {
            int gn = n0 + wn + nt * 16 + lrow;
            float bv = bias[gn];
            int h = gn >> 6, d = gn & 63;
            for (int mt = 0; mt < 4; mt++) {
                int gm0 = m0 + wm + mt * 16 + lquad * 4;  // multiple of 4
                int b = gm0 >> 12, s = gm0 & (SS - 1);
                short4v pk;
                for (int r = 0; r < 4; r++) pk[r] = f2bf(acc[mt][nt][r] + bv);
                *(short4v*)&Vto[(((size_t)(b * HH + h)) * DD + d) * SS + s] = pk;
            }
        }
    } else {
        short* out = (z == 0) ? Qo : Ko;
        float scale = (z == 0) ? 0.125f : 1.0f;
        for (int nt = 0; nt < 4; nt++) {
            int gn = n0 + wn + nt * 16 + lrow;
            float bv = bias[gn];
            int h = gn >> 6, d = gn & 63;
            for (int mt = 0; mt < 4; mt++) {
                int gmb = m0 + wm + mt * 16 + lquad * 4;
                for (int r = 0; r < 4; r++) {
                    int gm = gmb + r;
                    int b = gm >> 12, s = gm & (SS - 1);
                    float v = (acc[mt][nt][r] + bv) * scale;
                    out[(((size_t)(b * HH + h)) * SS + s) * DD + d] = f2bf(v);
                }
            }
        }
    }
}

// Sliding-window attention v2: 256 queries/block, K/V tiles staged in LDS and
// shared by all 4 waves. Scores computed transposed (S^T = K*Q^T).
// Q,K bf16 [B,H,S,D]; Vt bf16 [B,H,D,S]; out fp32 [B,S,E].
__global__ __launch_bounds__(256) void band_attn(
    const short* __restrict__ Q, const short* __restrict__ K,
    const short* __restrict__ Vt, float* __restrict__ out) {
    int b = blockIdx.z, h = blockIdx.y, chunk = blockIdx.x;
    int tid = threadIdx.x;
    int wave = tid >> 6, lane = tid & 63, lquad = lane >> 4, lrow = lane & 15;
    int qbase = chunk * 256 + wave * 64;  // this wave's 64 queries

    const short* Qh = Q + ((size_t)(b * HH + h)) * SS * DD;
    const short* Kh = K + ((size_t)(b * HH + h)) * SS * DD;
    const short* Vh = Vt + ((size_t)(b * HH + h)) * DD * SS;

    __shared__ __align__(16) short Ks[64 * 72];      // [key][d]
    __shared__ __align__(16) short Vs[64 * 72];      // [d][key]
    __shared__ __align__(16) short Ps[4][16 * 72];   // per wave: [q][key]
    short* Pw = &Ps[wave][0];

    // Persistent Q B-fragments: B[n=query=lrow][k=d=lquad*8+j], two K=32 halves
    short8 qf[4][2];
#pragma unroll
    for (int m = 0; m < 4; m++)
#pragma unroll
        for (int hh = 0; hh < 2; hh++)
            qf[m][hh] = *(const short8*)&Qh[(size_t)(qbase + m * 16 + lrow) * DD + hh * 32 + lquad * 8];

    floatx4 o[4][4] = {};
    float ls[4] = {0.0f, 0.0f, 0.0f, 0.0f};

    int kwin = chunk * 256 - WW;  // block's key-window start (12 tiles of 64)
    int srow = tid >> 3;          // 0..31
    int scol = (tid & 7) * 8;     // 0..56

    for (int t = 0; t < 12; t++) {
        int ks0 = kwin + t * 64;
        // --- stage K tile [64 keys x 64 d] and Vt tile [64 d x 64 keys] ---
#pragma unroll
        for (int i = 0; i < 2; i++) {
            int r = srow + i * 32;
            int gk = imin(imax(ks0 + r, 0), SS - 1);
            *(short8*)&Ks[r * 72 + scol] = *(const short8*)&Kh[(size_t)gk * DD + scol];
            int gv = imin(imax(ks0 + scol, 0), SS - 8);
            *(short8*)&Vs[r * 72 + scol] = *(const short8*)&Vh[(size_t)r * SS + gv];
        }
        __syncthreads();

        if ((unsigned)(t - wave) < 9u) {  // this wave's 576-key window
            short8 kf[4][2], vf[4][2];
#pragma unroll
            for (int kt = 0; kt < 4; kt++)
#pragma unroll
                for (int hh = 0; hh < 2; hh++)
                    kf[kt][hh] = *(short8*)&Ks[(kt * 16 + lrow) * 72 + hh * 32 + lquad * 8];
#pragma unroll
            for (int nt = 0; nt < 4; nt++)
#pragma unroll
                for (int hh = 0; hh < 2; hh++)
                    vf[nt][hh] = *(short8*)&Vs[(nt * 16 + lrow) * 72 + hh * 32 + lquad * 8];

#pragma unroll
            for (int m = 0; m < 4; m++) {
                int q = qbase + m * 16 + lrow;  // this lane's query (S^T: col = lane&15)
                floatx4 s[4];
#pragma unroll
                for (int kt = 0; kt < 4; kt++) {
                    floatx4 zz = {};
                    s[kt] = MFMA16(kf[kt][0], qf[m][0], zz);
                    s[kt] = MFMA16(kf[kt][1], qf[m][1], s[kt]);
                }
                float lacc = 0.0f;
#pragma unroll
                for (int kt = 0; kt < 4; kt++) {
                    short4v pk;
#pragma unroll
                    for (int r = 0; r < 4; r++) {
                        int key = ks0 + kt * 16 + lquad * 4 + r;
                        bool valid = ((unsigned)(key - q + WW) <= 2u * WW) && ((unsigned)key < SS);
                        float p = valid ? __expf(s[kt][r]) : 0.0f;
                        pk[r] = f2bf(p);
                        lacc += bf2f(pk[r]);
                    }
                    // 4 consecutive keys for query lrow: one packed 8B store
                    *(short4v*)&Pw[lrow * 72 + kt * 16 + lquad * 4] = pk;
                }
                ls[m] += lacc;
                asm volatile("" ::: "memory");  // order P write->read (same-wave DS is in-order)
                short8 ap0 = *(short8*)&Pw[lrow * 72 + lquad * 8];
                short8 ap1 = *(short8*)&Pw[lrow * 72 + 32 + lquad * 8];
#pragma unroll
                for (int nt = 0; nt < 4; nt++) {
                    o[m][nt] = MFMA16(ap0, vf[nt][0], o[m][nt]);
                    o[m][nt] = MFMA16(ap1, vf[nt][1], o[m][nt]);
                }
            }
        }
        __syncthreads();
    }

    // ls[m]: per-lane partials over this lane's quad; reduce across quads
#pragma unroll
    for (int m = 0; m < 4; m++) {
        ls[m] += __shfl_xor(ls[m], 16, 64);
        ls[m] += __shfl_xor(ls[m], 32, 64);
        ls[m] = 1.0f / ls[m];  // lane L holds 1/ls for query (L&15)
    }

#pragma unroll
    for (int m = 0; m < 4; m++) {
#pragma unroll
        for (int r = 0; r < 4; r++) {
            float linv = __shfl(ls[m], lquad * 4 + r, 64);
            int s = qbase + m * 16 + lquad * 4 + r;
#pragma unroll
            for (int nt = 0; nt < 4; nt++)
                out[((size_t)b * SS + s) * EE + h * DD + nt * 16 + lrow] = o[m][nt][r] * linv;
        }
    }
}

extern "C" void kernel_launch(void* const* d_in, const int* in_sizes, int n_in,
                              void* d_out, int out_size, void* d_ws, size_t ws_size,
                              hipStream_t stream) {
    const float* hidden = (const float*)d_in[0];
    const float* Wq = (const float*)d_in[1];
    const float* bq = (const float*)d_in[2];
    const float* Wk = (const float*)d_in[3];
    const float* bk = (const float*)d_in[4];
    const float* Wv = (const float*)d_in[5];
    const float* bv = (const float*)d_in[6];
    float* out = (float*)d_out;

    short* ws = (short*)d_ws;
    const size_t WSZ = (size_t)EE * EE;            // 589824
    const size_t QSZ = (size_t)BB * HH * SS * DD;  // 6291456
    short* Wt = ws;              // 3 * WSZ  (bf16)
    short* Qb = Wt + 3 * WSZ;    // Q  [B,H,S,D] bf16
    short* Kb = Qb + QSZ;        // K  [B,H,S,D] bf16
    short* Vtb = Kb + QSZ;       // Vt [B,H,D,S] bf16
    // ws total: 3*WSZ + 3*QSZ shorts = 41.3 MB
    // Xb (bf16 X, 12.6 MB) lives in d_out (25 MB fp32) — consumed by qkv_gemm
    // before band_attn overwrites d_out at the end of the stream.
    short* Xb = (short*)d_out;

    convert_x<<<dim3((BB * SS * EE) / (256 * 8), 1, 1), 256, 0, stream>>>(hidden, Xb);
    transpose_w<<<dim3(24, 24, 3), dim3(32, 8, 1), 0, stream>>>(Wq, Wk, Wv, Wt);

    qkv_gemm<<<dim3(64, 6, 3), 256, 0, stream>>>(Xb, Wt, bq, bk, bv, Qb, Kb, Vtb);

    band_attn<<<dim3(SS / 256, HH, BB), 256, 0, stream>>>(Qb, Kb, Vtb, out);
}

// Round 6
// 191.971 us; speedup vs baseline: 1.3725x; 1.0211x over previous
//
#include <hip/hip_runtime.h>

#define BB 2
#define SS 4096
#define EE 768
#define HH 12
#define DD 64
#define WW 256

typedef __attribute__((ext_vector_type(8))) short short8;
typedef __attribute__((ext_vector_type(4))) short short4v;
typedef __attribute__((ext_vector_type(4))) float floatx4;

#define MFMA16(a, b, c) __builtin_amdgcn_mfma_f32_16x16x32_bf16(a, b, c, 0, 0, 0)

__device__ __forceinline__ float bf2f(short x) {
    union { unsigned u; float f; } v;
    v.u = ((unsigned)(unsigned short)x) << 16;
    return v.f;
}

__device__ __forceinline__ short f2bf(float x) {
    union { float f; unsigned u; } v;
    v.f = x;
    unsigned r = v.u + 0x7fffu + ((v.u >> 16) & 1u);  // RNE
    return (short)(r >> 16);
}

__device__ __forceinline__ int imin(int a, int b) { return a < b ? a : b; }
__device__ __forceinline__ int imax(int a, int b) { return a > b ? a : b; }

// async global->LDS, 16B per lane; LDS dest must be wave-uniform-base + lane*16
__device__ __forceinline__ void gload_lds16(const short* g, short* l) {
    __builtin_amdgcn_global_load_lds(
        (const __attribute__((address_space(1))) unsigned*)g,
        (__attribute__((address_space(3))) unsigned*)l, 16, 0, 0);
}

// fp32 -> bf16 bulk convert (X), 8 elems/thread
__global__ __launch_bounds__(256) void convert_x(const float* __restrict__ in,
                                                 short* __restrict__ out) {
    int i = blockIdx.x * 256 + threadIdx.x;
    const floatx4* src = (const floatx4*)(in + (size_t)i * 8);
    floatx4 f0 = src[0], f1 = src[1];
    short8 s8;
#pragma unroll
    for (int j = 0; j < 4; j++) { s8[j] = f2bf(f0[j]); s8[j + 4] = f2bf(f1[j]); }
    *(short8*)(out + (size_t)i * 8) = s8;
}

// out[z][c][r] = bf16(in_z[r][c]) for the three 768x768 weight matrices
__global__ void transpose_w(const float* __restrict__ W0, const float* __restrict__ W1,
                            const float* __restrict__ W2, short* __restrict__ out) {
    __shared__ short t[32][33];
    int z = blockIdx.z;
    const float* in = (z == 0) ? W0 : (z == 1) ? W1 : W2;
    short* op = out + (size_t)z * EE * EE;
    int tx = threadIdx.x, ty = threadIdx.y;  // 32 x 8
    int x = blockIdx.x * 32 + tx;
    int y0 = blockIdx.y * 32;
    for (int j = 0; j < 32; j += 8) t[ty + j][tx] = f2bf(in[(size_t)(y0 + ty + j) * EE + x]);
    __syncthreads();
    int x2 = y0 + tx;
    int y2 = blockIdx.x * 32;
    for (int j = 0; j < 32; j += 8) op[(size_t)(y2 + ty + j) * EE + x2] = t[tx][ty + j];
}

// C = Xb * W^T(+bias), Xb bf16:[8192][768], Wt bf16:[3][768(n)][768(k)]
// z=0: Q*(1/8) -> [B,H,S,D];  z=1: K -> [B,H,S,D];  z=2: V -> [B,H,D,S]
// BK=64 K-steps; LDS col-group XOR-swizzled (g_lds = g ^ (row&7)) so the
// fragment reads are bank-conflict-free without padding (global_load_lds
// requires the contiguous lane->LDS mapping, so padding is not an option).
__global__ __launch_bounds__(256) void qkv_gemm(
    const short* __restrict__ Xb, const short* __restrict__ Wt,
    const float* __restrict__ Bq, const float* __restrict__ Bk, const float* __restrict__ Bv,
    short* __restrict__ Qo, short* __restrict__ Ko, short* __restrict__ Vto) {
    int z = blockIdx.z;
    const short* Wz = Wt + (size_t)z * EE * EE;
    const float* bias = (z == 0) ? Bq : (z == 1) ? Bk : Bv;

    __shared__ __align__(16) short As[128 * 64];  // 16 KB
    __shared__ __align__(16) short Bs[128 * 64];  // 16 KB
    int tid = threadIdx.x;
    int m0 = blockIdx.x * 128, n0 = blockIdx.y * 128;
    int wave = tid >> 6, lane = tid & 63, lquad = lane >> 4, lrow = lane & 15;
    int wm = (wave & 1) * 64, wn = (wave >> 1) * 64;

    floatx4 acc[4][4] = {};

    // staging: chunk c = 256*i + tid (i=0..3); row = c>>3 = 32*i + (tid>>3),
    // LDS col-group = c&7 = tid&7, swizzled source col-group = (tid&7)^(row&7).
    int srow = tid >> 3;                        // 0..31
    int gsrc = ((tid & 7) ^ (srow & 7)) * 8;    // source col offset (shorts)
    // fragment read swizzle: e = ((lquad ^ (lrow&7)) ^ (half<<2)) * 8
    int e0 = (lquad ^ (lrow & 7)) * 8;

    for (int k0 = 0; k0 < EE; k0 += 64) {
#pragma unroll
        for (int i = 0; i < 4; i++) {
            int row = 32 * i + srow;
            gload_lds16(&Xb[(size_t)(m0 + row) * EE + k0 + gsrc], &As[(256 * i + tid) * 8]);
            gload_lds16(&Wz[(size_t)(n0 + row) * EE + k0 + gsrc], &Bs[(256 * i + tid) * 8]);
        }
        __syncthreads();
#pragma unroll
        for (int half = 0; half < 2; half++) {
            int e = e0 ^ (half << 5);  // (e0/8 ^ (half*4)) * 8
            short8 af[4], bfv[4];
#pragma unroll
            for (int mt = 0; mt < 4; mt++)
                af[mt] = *(short8*)&As[(wm + mt * 16 + lrow) * 64 + e];
#pragma unroll
            for (int nt = 0; nt < 4; nt++)
                bfv[nt] = *(short8*)&Bs[(wn + nt * 16 + lrow) * 64 + e];
#pragma unroll
            for (int mt = 0; mt < 4; mt++)
#pragma unroll
                for (int nt = 0; nt < 4; nt++)
                    acc[mt][nt] = MFMA16(af[mt], bfv[nt], acc[mt][nt]);
        }
        __syncthreads();
    }

    if (z == 2) {
        // V, stored transposed: Vt[b,h,d,s]
        for (int nt = 0; nt < 4; nt++) {
            int gn = n0 + wn + nt * 16 + lrow;
            float bv = bias[gn];
            int h = gn >> 6, d = gn & 63;
            for (int mt = 0; mt < 4; mt++) {
                int gm0 = m0 + wm + mt * 16 + lquad * 4;  // multiple of 4
                int b = gm0 >> 12, s = gm0 & (SS - 1);
                short4v pk;
                for (int r = 0; r < 4; r++) pk[r] = f2bf(acc[mt][nt][r] + bv);
                *(short4v*)&Vto[(((size_t)(b * HH + h)) * DD + d) * SS + s] = pk;
            }
        }
    } else {
        short* out = (z == 0) ? Qo : Ko;
        float scale = (z == 0) ? 0.125f : 1.0f;
        for (int nt = 0; nt < 4; nt++) {
            int gn = n0 + wn + nt * 16 + lrow;
            float bv = bias[gn];
            int h = gn >> 6, d = gn & 63;
            for (int mt = 0; mt < 4; mt++) {
                int gmb = m0 + wm + mt * 16 + lquad * 4;
                for (int r = 0; r < 4; r++) {
                    int gm = gmb + r;
                    int b = gm >> 12, s = gm & (SS - 1);
                    float v = (acc[mt][nt][r] + bv) * scale;
                    out[(((size_t)(b * HH + h)) * SS + s) * DD + d] = f2bf(v);
                }
            }
        }
    }
}

// Sliding-window attention v2: 256 queries/block, K/V tiles staged in LDS and
// shared by all 4 waves. Scores computed transposed (S^T = K*Q^T).
// Q,K bf16 [B,H,S,D]; Vt bf16 [B,H,D,S]; out fp32 [B,S,E].
__global__ __launch_bounds__(256) void band_attn(
    const short* __restrict__ Q, const short* __restrict__ K,
    const short* __restrict__ Vt, float* __restrict__ out) {
    int b = blockIdx.z, h = blockIdx.y, chunk = blockIdx.x;
    int tid = threadIdx.x;
    int wave = tid >> 6, lane = tid & 63, lquad = lane >> 4, lrow = lane & 15;
    int qbase = chunk * 256 + wave * 64;  // this wave's 64 queries

    const short* Qh = Q + ((size_t)(b * HH + h)) * SS * DD;
    const short* Kh = K + ((size_t)(b * HH + h)) * SS * DD;
    const short* Vh = Vt + ((size_t)(b * HH + h)) * DD * SS;

    __shared__ __align__(16) short Ks[64 * 72];      // [key][d]
    __shared__ __align__(16) short Vs[64 * 72];      // [d][key]
    __shared__ __align__(16) short Ps[4][16 * 72];   // per wave: [q][key]
    short* Pw = &Ps[wave][0];

    // Persistent Q B-fragments: B[n=query=lrow][k=d=lquad*8+j], two K=32 halves
    short8 qf[4][2];
#pragma unroll
    for (int m = 0; m < 4; m++)
#pragma unroll
        for (int hh = 0; hh < 2; hh++)
            qf[m][hh] = *(const short8*)&Qh[(size_t)(qbase + m * 16 + lrow) * DD + hh * 32 + lquad * 8];

    floatx4 o[4][4] = {};
    float ls[4] = {0.0f, 0.0f, 0.0f, 0.0f};

    int kwin = chunk * 256 - WW;  // block's key-window start (12 tiles of 64)
    int srow = tid >> 3;          // 0..31
    int scol = (tid & 7) * 8;     // 0..56

    for (int t = 0; t < 12; t++) {
        int ks0 = kwin + t * 64;
        // --- stage K tile [64 keys x 64 d] and Vt tile [64 d x 64 keys] ---
#pragma unroll
        for (int i = 0; i < 2; i++) {
            int r = srow + i * 32;
            int gk = imin(imax(ks0 + r, 0), SS - 1);
            *(short8*)&Ks[r * 72 + scol] = *(const short8*)&Kh[(size_t)gk * DD + scol];
            int gv = imin(imax(ks0 + scol, 0), SS - 8);
            *(short8*)&Vs[r * 72 + scol] = *(const short8*)&Vh[(size_t)r * SS + gv];
        }
        __syncthreads();

        if ((unsigned)(t - wave) < 9u) {  // this wave's 576-key window
            short8 kf[4][2], vf[4][2];
#pragma unroll
            for (int kt = 0; kt < 4; kt++)
#pragma unroll
                for (int hh = 0; hh < 2; hh++)
                    kf[kt][hh] = *(short8*)&Ks[(kt * 16 + lrow) * 72 + hh * 32 + lquad * 8];
#pragma unroll
            for (int nt = 0; nt < 4; nt++)
#pragma unroll
                for (int hh = 0; hh < 2; hh++)
                    vf[nt][hh] = *(short8*)&Vs[(nt * 16 + lrow) * 72 + hh * 32 + lquad * 8];

#pragma unroll
            for (int m = 0; m < 4; m++) {
                int q = qbase + m * 16 + lrow;  // this lane's query (S^T: col = lane&15)
                floatx4 s[4];
#pragma unroll
                for (int kt = 0; kt < 4; kt++) {
                    floatx4 zz = {};
                    s[kt] = MFMA16(kf[kt][0], qf[m][0], zz);
                    s[kt] = MFMA16(kf[kt][1], qf[m][1], s[kt]);
                }
                float lacc = 0.0f;
#pragma unroll
                for (int kt = 0; kt < 4; kt++) {
                    short4v pk;
#pragma unroll
                    for (int r = 0; r < 4; r++) {
                        int key = ks0 + kt * 16 + lquad * 4 + r;
                        bool valid = ((unsigned)(key - q + WW) <= 2u * WW) && ((unsigned)key < SS);
                        float p = valid ? __expf(s[kt][r]) : 0.0f;
                        pk[r] = f2bf(p);
                        lacc += bf2f(pk[r]);
                    }
                    // 4 consecutive keys for query lrow: one packed 8B store
                    *(short4v*)&Pw[lrow * 72 + kt * 16 + lquad * 4] = pk;
                }
                ls[m] += lacc;
                asm volatile("" ::: "memory");  // order P write->read (same-wave DS is in-order)
                short8 ap0 = *(short8*)&Pw[lrow * 72 + lquad * 8];
                short8 ap1 = *(short8*)&Pw[lrow * 72 + 32 + lquad * 8];
#pragma unroll
                for (int nt = 0; nt < 4; nt++) {
                    o[m][nt] = MFMA16(ap0, vf[nt][0], o[m][nt]);
                    o[m][nt] = MFMA16(ap1, vf[nt][1], o[m][nt]);
                }
            }
        }
        __syncthreads();
    }

    // ls[m]: per-lane partials over this lane's quad; reduce across quads
#pragma unroll
    for (int m = 0; m < 4; m++) {
        ls[m] += __shfl_xor(ls[m], 16, 64);
        ls[m] += __shfl_xor(ls[m], 32, 64);
        ls[m] = 1.0f / ls[m];  // lane L holds 1/ls for query (L&15)
    }

#pragma unroll
    for (int m = 0; m < 4; m++) {
#pragma unroll
        for (int r = 0; r < 4; r++) {
            float linv = __shfl(ls[m], lquad * 4 + r, 64);
            int s = qbase + m * 16 + lquad * 4 + r;
#pragma unroll
            for (int nt = 0; nt < 4; nt++)
                out[((size_t)b * SS + s) * EE + h * DD + nt * 16 + lrow] = o[m][nt][r] * linv;
        }
    }
}

extern "C" void kernel_launch(void* const* d_in, const int* in_sizes, int n_in,
                              void* d_out, int out_size, void* d_ws, size_t ws_size,
                              hipStream_t stream) {
    const float* hidden = (const float*)d_in[0];
    const float* Wq = (const float*)d_in[1];
    const float* bq = (const float*)d_in[2];
    const float* Wk = (const float*)d_in[3];
    const float* bk = (const float*)d_in[4];
    const float* Wv = (const float*)d_in[5];
    const float* bv = (const float*)d_in[6];
    float* out = (float*)d_out;

    short* ws = (short*)d_ws;
    const size_t WSZ = (size_t)EE * EE;            // 589824
    const size_t QSZ = (size_t)BB * HH * SS * DD;  // 6291456
    short* Wt = ws;              // 3 * WSZ  (bf16)
    short* Qb = Wt + 3 * WSZ;    // Q  [B,H,S,D] bf16
    short* Kb = Qb + QSZ;        // K  [B,H,S,D] bf16
    short* Vtb = Kb + QSZ;       // Vt [B,H,D,S] bf16
    // ws total: 3*WSZ + 3*QSZ shorts = 41.3 MB
    // Xb (bf16 X, 12.6 MB) lives in d_out (25 MB fp32) — consumed by qkv_gemm
    // before band_attn overwrites d_out at the end of the stream.
    short* Xb = (short*)d_out;

    convert_x<<<dim3((BB * SS * EE) / (256 * 8), 1, 1), 256, 0, stream>>>(hidden, Xb);
    transpose_w<<<dim3(24, 24, 3), dim3(32, 8, 1), 0, stream>>>(Wq, Wk, Wv, Wt);

    qkv_gemm<<<dim3(64, 6, 3), 256, 0, stream>>>(Xb, Wt, bq, bk, bv, Qb, Kb, Vtb);

    band_attn<<<dim3(SS / 256, HH, BB), 256, 0, stream>>>(Qb, Kb, Vtb, out);
}

// Round 7
// 185.280 us; speedup vs baseline: 1.4221x; 1.0361x over previous
//
#include <hip/hip_runtime.h>

#define BB 2
#define SS 4096
#define EE 768
#define HH 12
#define DD 64
#define WW 256

typedef __attribute__((ext_vector_type(8))) short short8;
typedef __attribute__((ext_vector_type(4))) short short4v;
typedef __attribute__((ext_vector_type(4))) float floatx4;

#define MFMA16(a, b, c) __builtin_amdgcn_mfma_f32_16x16x32_bf16(a, b, c, 0, 0, 0)

__device__ __forceinline__ float bf2f(short x) {
    union { unsigned u; float f; } v;
    v.u = ((unsigned)(unsigned short)x) << 16;
    return v.f;
}

__device__ __forceinline__ short f2bf(float x) {
    union { float f; unsigned u; } v;
    v.f = x;
    unsigned r = v.u + 0x7fffu + ((v.u >> 16) & 1u);  // RNE
    return (short)(r >> 16);
}

__device__ __forceinline__ int imin(int a, int b) { return a < b ? a : b; }
__device__ __forceinline__ int imax(int a, int b) { return a > b ? a : b; }

// async global->LDS, 16B per lane; LDS dest must be wave-uniform-base + lane*16
__device__ __forceinline__ void gload_lds16(const short* g, short* l) {
    __builtin_amdgcn_global_load_lds(
        (const __attribute__((address_space(1))) unsigned*)g,
        (__attribute__((address_space(3))) unsigned*)l, 16, 0, 0);
}

// fp32 -> bf16 bulk convert (X), 8 elems/thread
__global__ __launch_bounds__(256) void convert_x(const float* __restrict__ in,
                                                 short* __restrict__ out) {
    int i = blockIdx.x * 256 + threadIdx.x;
    const floatx4* src = (const floatx4*)(in + (size_t)i * 8);
    floatx4 f0 = src[0], f1 = src[1];
    short8 s8;
#pragma unroll
    for (int j = 0; j < 4; j++) { s8[j] = f2bf(f0[j]); s8[j + 4] = f2bf(f1[j]); }
    *(short8*)(out + (size_t)i * 8) = s8;
}

// out[z][c][r] = bf16(in_z[r][c]) for the three 768x768 weight matrices
__global__ void transpose_w(const float* __restrict__ W0, const float* __restrict__ W1,
                            const float* __restrict__ W2, short* __restrict__ out) {
    __shared__ short t[32][33];
    int z = blockIdx.z;
    const float* in = (z == 0) ? W0 : (z == 1) ? W1 : W2;
    short* op = out + (size_t)z * EE * EE;
    int tx = threadIdx.x, ty = threadIdx.y;  // 32 x 8
    int x = blockIdx.x * 32 + tx;
    int y0 = blockIdx.y * 32;
    for (int j = 0; j < 32; j += 8) t[ty + j][tx] = f2bf(in[(size_t)(y0 + ty + j) * EE + x]);
    __syncthreads();
    int x2 = y0 + tx;
    int y2 = blockIdx.x * 32;
    for (int j = 0; j < 32; j += 8) op[(size_t)(y2 + ty + j) * EE + x2] = t[tx][ty + j];
}

// C = Xb * W^T(+bias), Xb bf16:[8192][768], Wt bf16:[3][768(n)][768(k)]
// z=0: Q*(1/8) -> [B,H,S,D];  z=1: K -> [B,H,S,D];  z=2: V -> [B,H,D,S]
// Round-5 structure (BK=32, unpadded, global_load_lds w16) — measured 62.5 us;
// BK=64+swizzle variant regressed (conflicts were overlapped latency, not cost).
__global__ __launch_bounds__(256) void qkv_gemm(
    const short* __restrict__ Xb, const short* __restrict__ Wt,
    const float* __restrict__ Bq, const float* __restrict__ Bk, const float* __restrict__ Bv,
    short* __restrict__ Qo, short* __restrict__ Ko, short* __restrict__ Vto) {
    int z = blockIdx.z;
    const short* Wz = Wt + (size_t)z * EE * EE;
    const float* bias = (z == 0) ? Bq : (z == 1) ? Bk : Bv;

    __shared__ __align__(16) short As[128 * 32];
    __shared__ __align__(16) short Bs[128 * 32];
    int tid = threadIdx.x;
    int m0 = blockIdx.x * 128, n0 = blockIdx.y * 128;
    int wave = tid >> 6, lane = tid & 63, lquad = lane >> 4, lrow = lane & 15;
    int wm = (wave & 1) * 64, wn = (wave >> 1) * 64;

    floatx4 acc[4][4] = {};

    // staging chunks: c = j*256 + tid; row = c>>2, col = (c&3)*8 shorts
    int c0 = tid, c1 = 256 + tid;
    int r0s = c0 >> 2, c0s = (c0 & 3) * 8;
    int r1s = c1 >> 2, c1s = (c1 & 3) * 8;

    for (int k0 = 0; k0 < EE; k0 += 32) {
        gload_lds16(&Xb[(size_t)(m0 + r0s) * EE + k0 + c0s], &As[c0 * 8]);
        gload_lds16(&Wz[(size_t)(n0 + r0s) * EE + k0 + c0s], &Bs[c0 * 8]);
        gload_lds16(&Xb[(size_t)(m0 + r1s) * EE + k0 + c1s], &As[c1 * 8]);
        gload_lds16(&Wz[(size_t)(n0 + r1s) * EE + k0 + c1s], &Bs[c1 * 8]);
        __syncthreads();
        short8 af[4], bfv[4];
#pragma unroll
        for (int mt = 0; mt < 4; mt++)
            af[mt] = *(short8*)&As[(wm + mt * 16 + lrow) * 32 + lquad * 8];
#pragma unroll
        for (int nt = 0; nt < 4; nt++)
            bfv[nt] = *(short8*)&Bs[(wn + nt * 16 + lrow) * 32 + lquad * 8];
#pragma unroll
        for (int mt = 0; mt < 4; mt++)
#pragma unroll
            for (int nt = 0; nt < 4; nt++)
                acc[mt][nt] = MFMA16(af[mt], bfv[nt], acc[mt][nt]);
        __syncthreads();
    }

    if (z == 2) {
        // V, stored transposed: Vt[b,h,d,s]
        for (int nt = 0; nt < 4; nt++) {
            int gn = n0 + wn + nt * 16 + lrow;
            float bv = bias[gn];
            int h = gn >> 6, d = gn & 63;
            for (int mt = 0; mt < 4; mt++) {
                int gm0 = m0 + wm + mt * 16 + lquad * 4;  // multiple of 4
                int b = gm0 >> 12, s = gm0 & (SS - 1);
                short4v pk;
                for (int r = 0; r < 4; r++) pk[r] = f2bf(acc[mt][nt][r] + bv);
                *(short4v*)&Vto[(((size_t)(b * HH + h)) * DD + d) * SS + s] = pk;
            }
        }
    } else {
        short* out = (z == 0) ? Qo : Ko;
        float scale = (z == 0) ? 0.125f : 1.0f;
        for (int nt = 0; nt < 4; nt++) {
            int gn = n0 + wn + nt * 16 + lrow;
            float bv = bias[gn];
            int h = gn >> 6, d = gn & 63;
            for (int mt = 0; mt < 4; mt++) {
                int gmb = m0 + wm + mt * 16 + lquad * 4;
                for (int r = 0; r < 4; r++) {
                    int gm = gmb + r;
                    int b = gm >> 12, s = gm & (SS - 1);
                    float v = (acc[mt][nt][r] + bv) * scale;
                    out[(((size_t)(b * HH + h)) * SS + s) * DD + d] = f2bf(v);
                }
            }
        }
    }
}

// Sliding-window attention v3: 128 queries/block (4 waves x 32 queries) for
// 2x grid (768 blocks, ~3/CU). 10-tile staged window, 9 active tiles/wave.
// Grid (hb=24, chunk=32): consecutive chunks differ by 24 blocks = 0 mod 8
// -> same XCD -> a head's K/V (2 MB) stays resident in that XCD's L2.
// S^T = K*Q^T trick as v2. Q,K bf16 [B,H,S,D]; Vt bf16 [B,H,D,S]; out fp32.
__global__ __launch_bounds__(256) void band_attn(
    const short* __restrict__ Q, const short* __restrict__ K,
    const short* __restrict__ Vt, float* __restrict__ out) {
    int hb = blockIdx.x;  // 0..23
    int h = hb % HH, b = hb / HH;
    int chunk = blockIdx.y;  // 0..31, 128 queries
    int tid = threadIdx.x;
    int wave = tid >> 6, lane = tid & 63, lquad = lane >> 4, lrow = lane & 15;
    int qbase = chunk * 128 + wave * 32;  // this wave's 32 queries

    const short* Qh = Q + ((size_t)(b * HH + h)) * SS * DD;
    const short* Kh = K + ((size_t)(b * HH + h)) * SS * DD;
    const short* Vh = Vt + ((size_t)(b * HH + h)) * DD * SS;

    __shared__ __align__(16) short Ks[64 * 72];     // [key][d]
    __shared__ __align__(16) short Vs[64 * 72];     // [d][key]
    __shared__ __align__(16) short Ps[4][16 * 72];  // per wave: [q][key]
    short* Pw = &Ps[wave][0];

    // Persistent Q B-fragments for 2 m-tiles: B[n=query=lrow][k=d=lquad*8+j]
    short8 qf[2][2];
#pragma unroll
    for (int m = 0; m < 2; m++)
#pragma unroll
        for (int hh = 0; hh < 2; hh++)
            qf[m][hh] = *(const short8*)&Qh[(size_t)(qbase + m * 16 + lrow) * DD + hh * 32 + lquad * 8];

    floatx4 o[2][4] = {};
    float ls[2] = {0.0f, 0.0f};

    int kwin = chunk * 128 - WW;  // block's key-window start (10 tiles of 64)
    int srow = tid >> 3;          // 0..31
    int scol = (tid & 7) * 8;     // 0..56
    int tlo = wave >> 1;          // wave active on tiles [tlo, tlo+9)

    for (int t = 0; t < 10; t++) {
        int ks0 = kwin + t * 64;
        // --- stage K tile [64 keys x 64 d] and Vt tile [64 d x 64 keys] ---
#pragma unroll
        for (int i = 0; i < 2; i++) {
            int r = srow + i * 32;
            int gk = imin(imax(ks0 + r, 0), SS - 1);
            *(short8*)&Ks[r * 72 + scol] = *(const short8*)&Kh[(size_t)gk * DD + scol];
            int gv = imin(imax(ks0 + scol, 0), SS - 8);
            *(short8*)&Vs[r * 72 + scol] = *(const short8*)&Vh[(size_t)r * SS + gv];
        }
        __syncthreads();

        if ((unsigned)(t - tlo) < 9u) {  // this wave's 544-key window
            short8 kf[4][2], vf[4][2];
#pragma unroll
            for (int kt = 0; kt < 4; kt++)
#pragma unroll
                for (int hh = 0; hh < 2; hh++)
                    kf[kt][hh] = *(short8*)&Ks[(kt * 16 + lrow) * 72 + hh * 32 + lquad * 8];
#pragma unroll
            for (int nt = 0; nt < 4; nt++)
#pragma unroll
                for (int hh = 0; hh < 2; hh++)
                    vf[nt][hh] = *(short8*)&Vs[(nt * 16 + lrow) * 72 + hh * 32 + lquad * 8];

#pragma unroll
            for (int m = 0; m < 2; m++) {
                int q = qbase + m * 16 + lrow;  // this lane's query (S^T: col = lane&15)
                floatx4 s[4];
#pragma unroll
                for (int kt = 0; kt < 4; kt++) {
                    floatx4 zz = {};
                    s[kt] = MFMA16(kf[kt][0], qf[m][0], zz);
                    s[kt] = MFMA16(kf[kt][1], qf[m][1], s[kt]);
                }
                float lacc = 0.0f;
#pragma unroll
                for (int kt = 0; kt < 4; kt++) {
                    short4v pk;
#pragma unroll
                    for (int r = 0; r < 4; r++) {
                        int key = ks0 + kt * 16 + lquad * 4 + r;
                        bool valid = ((unsigned)(key - q + WW) <= 2u * WW) && ((unsigned)key < SS);
                        float p = valid ? __expf(s[kt][r]) : 0.0f;
                        pk[r] = f2bf(p);
                        lacc += bf2f(pk[r]);
                    }
                    // 4 consecutive keys for query lrow: one packed 8B store
                    *(short4v*)&Pw[lrow * 72 + kt * 16 + lquad * 4] = pk;
                }
                ls[m] += lacc;
                asm volatile("" ::: "memory");  // order P write->read (same-wave DS is in-order)
                short8 ap0 = *(short8*)&Pw[lrow * 72 + lquad * 8];
                short8 ap1 = *(short8*)&Pw[lrow * 72 + 32 + lquad * 8];
#pragma unroll
                for (int nt = 0; nt < 4; nt++) {
                    o[m][nt] = MFMA16(ap0, vf[nt][0], o[m][nt]);
                    o[m][nt] = MFMA16(ap1, vf[nt][1], o[m][nt]);
                }
            }
        }
        __syncthreads();
    }

    // ls[m]: per-lane partials over this lane's quad; reduce across quads
#pragma unroll
    for (int m = 0; m < 2; m++) {
        ls[m] += __shfl_xor(ls[m], 16, 64);
        ls[m] += __shfl_xor(ls[m], 32, 64);
        ls[m] = 1.0f / ls[m];  // lane L holds 1/ls for query (L&15)
    }

#pragma unroll
    for (int m = 0; m < 2; m++) {
#pragma unroll
        for (int r = 0; r < 4; r++) {
            float linv = __shfl(ls[m], lquad * 4 + r, 64);
            int s = qbase + m * 16 + lquad * 4 + r;
#pragma unroll
            for (int nt = 0; nt < 4; nt++)
                out[((size_t)b * SS + s) * EE + h * DD + nt * 16 + lrow] = o[m][nt][r] * linv;
        }
    }
}

extern "C" void kernel_launch(void* const* d_in, const int* in_sizes, int n_in,
                              void* d_out, int out_size, void* d_ws, size_t ws_size,
                              hipStream_t stream) {
    const float* hidden = (const float*)d_in[0];
    const float* Wq = (const float*)d_in[1];
    const float* bq = (const float*)d_in[2];
    const float* Wk = (const float*)d_in[3];
    const float* bk = (const float*)d_in[4];
    const float* Wv = (const float*)d_in[5];
    const float* bv = (const float*)d_in[6];
    float* out = (float*)d_out;

    short* ws = (short*)d_ws;
    const size_t WSZ = (size_t)EE * EE;            // 589824
    const size_t QSZ = (size_t)BB * HH * SS * DD;  // 6291456
    short* Wt = ws;              // 3 * WSZ  (bf16)
    short* Qb = Wt + 3 * WSZ;    // Q  [B,H,S,D] bf16
    short* Kb = Qb + QSZ;        // K  [B,H,S,D] bf16
    short* Vtb = Kb + QSZ;       // Vt [B,H,D,S] bf16
    // ws total: 3*WSZ + 3*QSZ shorts = 41.3 MB
    // Xb (bf16 X, 12.6 MB) lives in d_out (25 MB fp32) — consumed by qkv_gemm
    // before band_attn overwrites d_out at the end of the stream.
    short* Xb = (short*)d_out;

    convert_x<<<dim3((BB * SS * EE) / (256 * 8), 1, 1), 256, 0, stream>>>(hidden, Xb);
    transpose_w<<<dim3(24, 24, 3), dim3(32, 8, 1), 0, stream>>>(Wq, Wk, Wv, Wt);

    qkv_gemm<<<dim3(64, 6, 3), 256, 0, stream>>>(Xb, Wt, bq, bk, bv, Qb, Kb, Vtb);

    band_attn<<<dim3(HH * BB, SS / 128, 1), 256, 0, stream>>>(Qb, Kb, Vtb, out);
}